// Round 2
// baseline (259.611 us; speedup 1.0000x reference)
//
#include <hip/hip_runtime.h>
#include <hip/hip_bf16.h>

typedef __bf16 bf16x8 __attribute__((ext_vector_type(8)));
typedef unsigned short u16x8 __attribute__((ext_vector_type(8)));
typedef float f32x4 __attribute__((ext_vector_type(4)));

// ---------------------------------------------------------------------------
// Prep: pack W1 [1280x32] and W2 [32x128] (f32, row-major) into bf16 MFMA
// B-fragment order for mfma_f32_16x16x32_bf16.
// Fragment element (lane l, elem j) <- W[k = kt*32 + (l>>4)*8 + j][n = nt*16 + (l&15)]
// (the (l>>4,j)->k bijection cancels against the identical A-side packing)
// wsB1[((kt*2+nt)*64 + l)*8 + j], wsB2[((nt)*64 + l)*8 + j]
// ---------------------------------------------------------------------------
__global__ __launch_bounds__(256) void prep_w_kernel(
    const float* __restrict__ W1, const float* __restrict__ W2,
    unsigned short* __restrict__ wsB1, unsigned short* __restrict__ wsB2) {
  int tid = blockIdx.x * 256 + threadIdx.x;
  if (tid < 40960) {                      // W1 frags: 40 ktiles * 2 ntiles * 512
    int j = tid & 7, l = (tid >> 3) & 63, nt = (tid >> 9) & 1, kt = tid >> 10;
    int k = kt * 32 + ((l >> 4) << 3) + j;
    int n = nt * 16 + (l & 15);
    __bf16 v = (__bf16)W1[k * 32 + n];
    wsB1[tid] = __builtin_bit_cast(unsigned short, v);
  } else if (tid < 45056) {               // W2 frags: 8 ntiles * 512
    int t = tid - 40960;
    int j = t & 7, l = (t >> 3) & 63, nt = t >> 9;
    int k = ((l >> 4) << 3) + j;
    int n = nt * 16 + (l & 15);
    __bf16 v = (__bf16)W2[k * 128 + n];
    wsB2[t] = __builtin_bit_cast(unsigned short, v);
  }
}

// ---------------------------------------------------------------------------
// Main: one wave per strip of 16 edges.
// GEMM1: h[16][32] = elu(x[16][1280] @ W1 + b1), 40 ktiles x 2 ntiles MFMA,
// with an explicit register-prefetch pipeline: depth DX=6 on the HBM x-stream,
// depth DW=3 on the L2-resident weight-fragment stream. Fully unrolled so all
// prefetch-array indices are compile-time constants (no scratch spill).
// Then transpose h via per-wave LDS, GEMM2: out[16][128] = h @ W2 + b2.
// ---------------------------------------------------------------------------
template <bool USE_WS>
__global__ __launch_bounds__(256) void edge_mlp_kernel(
    const float* __restrict__ src, const float* __restrict__ dst,
    const float* __restrict__ ea, const float* __restrict__ W1,
    const float* __restrict__ b1, const float* __restrict__ W2,
    const float* __restrict__ b2, const unsigned short* __restrict__ wsB1,
    const unsigned short* __restrict__ wsB2, float* __restrict__ out, int nE) {
  __shared__ alignas(16) unsigned short hbuf_s[4][16 * 40];  // 40 = padded row stride
  const int lane = threadIdx.x & 63;
  const int wave = threadIdx.x >> 6;
  const int l15 = lane & 15;
  const int lh = lane >> 4;
  const long strip = (long)blockIdx.x * 4 + wave;
  const long e0 = strip * 16;
  if (e0 >= nE) return;
  long row = e0 + l15;
  if (row >= nE) row = nE - 1;  // clamp; stores for OOB edges are predicated

  const float* psrc = src + row * 512 + lh * 8;
  const float* pdst = dst + row * 512 + lh * 8;
  const float* pea = ea + row * 256 + lh * 8;
  const unsigned short* pw1 = wsB1 + lane * 8;

  f32x4 acc0 = {0.f, 0.f, 0.f, 0.f};
  f32x4 acc1 = {0.f, 0.f, 0.f, 0.f};

  // static-index address helper (t is always a compile-time constant here)
  auto xptr = [&](int t) -> const float* {
    return (t < 16) ? (psrc + t * 32)
         : (t < 32) ? (pdst + (t - 16) * 32)
                    : (pea + (t - 32) * 32);
  };

  constexpr int DX = 6;  // x prefetch depth (HBM, ~900 cy)
  constexpr int DW = 3;  // weight-frag prefetch depth (L2, ~200 cy)
  f32x4 px[DX][2];
  u16x8 pw[DW][2];

#pragma unroll
  for (int t = 0; t < DX; ++t) {
    const float* p = xptr(t);
    px[t][0] = *(const f32x4*)p;
    px[t][1] = *(const f32x4*)(p + 4);
  }
  if constexpr (USE_WS) {
#pragma unroll
    for (int t = 0; t < DW; ++t) {
      pw[t][0] = *(const u16x8*)(pw1 + t * 1024);
      pw[t][1] = *(const u16x8*)(pw1 + t * 1024 + 512);
    }
  }

#pragma unroll
  for (int t = 0; t < 40; ++t) {
    f32x4 lo = px[t % DX][0];
    f32x4 hi = px[t % DX][1];
    bf16x8 bf0, bf1;
    if constexpr (USE_WS) {
      bf0 = __builtin_bit_cast(bf16x8, pw[t % DW][0]);
      bf1 = __builtin_bit_cast(bf16x8, pw[t % DW][1]);
    } else {
#pragma unroll
      for (int j = 0; j < 8; ++j) {
        int k = t * 32 + lh * 8 + j;
        bf0[j] = (__bf16)W1[k * 32 + l15];
        bf1[j] = (__bf16)W1[k * 32 + 16 + l15];
      }
    }
    // refill the slots just vacated (issues sink below the vmcnt of tile t's
    // consumers only via data deps; loads are independent -> scheduler hoists)
    if (t + DX < 40) {
      const float* p = xptr(t + DX);
      px[t % DX][0] = *(const f32x4*)p;
      px[t % DX][1] = *(const f32x4*)(p + 4);
    }
    if constexpr (USE_WS) {
      if (t + DW < 40) {
        pw[t % DW][0] = *(const u16x8*)(pw1 + (t + DW) * 1024);
        pw[t % DW][1] = *(const u16x8*)(pw1 + (t + DW) * 1024 + 512);
      }
    }
    bf16x8 a;
    a[0] = (__bf16)lo[0]; a[1] = (__bf16)lo[1];
    a[2] = (__bf16)lo[2]; a[3] = (__bf16)lo[3];
    a[4] = (__bf16)hi[0]; a[5] = (__bf16)hi[1];
    a[6] = (__bf16)hi[2]; a[7] = (__bf16)hi[3];
    acc0 = __builtin_amdgcn_mfma_f32_16x16x32_bf16(a, bf0, acc0, 0, 0, 0);
    acc1 = __builtin_amdgcn_mfma_f32_16x16x32_bf16(a, bf1, acc1, 0, 0, 0);
  }

  // ---- bias + ELU, write h (bf16) to LDS in C-layout positions ----
  const float bias0 = b1[l15];
  const float bias1 = b1[16 + l15];
  unsigned short* hl = hbuf_s[wave];
#pragma unroll
  for (int r = 0; r < 4; ++r) {
    int hrow = lh * 4 + r;  // C/D layout: row=(lane>>4)*4+reg, col=lane&15
    float h0 = acc0[r] + bias0;
    float h1 = acc1[r] + bias1;
    h0 = h0 > 0.f ? h0 : (__expf(h0) - 1.f);
    h1 = h1 > 0.f ? h1 : (__expf(h1) - 1.f);
    __bf16 v0 = (__bf16)h0, v1 = (__bf16)h1;
    hl[hrow * 40 + l15] = __builtin_bit_cast(unsigned short, v0);
    hl[hrow * 40 + 16 + l15] = __builtin_bit_cast(unsigned short, v1);
  }
  // wave-local: all lanes' ds_writes precede this in program order; drain them
  asm volatile("s_waitcnt lgkmcnt(0)" ::: "memory");
  // read back in A-fragment layout: lane l -> h[l&15][(l>>4)*8 + j]
  bf16x8 ha =
      __builtin_bit_cast(bf16x8, *(const u16x8*)(hl + l15 * 40 + lh * 8));

  // ---- GEMM2: out tiles over 8 ntiles of 16 cols ----
  f32x4 o[8];
#pragma unroll
  for (int nt = 0; nt < 8; ++nt) {
    bf16x8 bw;
    if (USE_WS) {
      bw = __builtin_bit_cast(bf16x8, *(const u16x8*)(wsB2 + nt * 512 + lane * 8));
    } else {
#pragma unroll
      for (int j = 0; j < 8; ++j)
        bw[j] = (__bf16)W2[(lh * 8 + j) * 128 + nt * 16 + l15];
    }
    f32x4 z = {0.f, 0.f, 0.f, 0.f};
    o[nt] = __builtin_amdgcn_mfma_f32_16x16x32_bf16(ha, bw, z, 0, 0, 0);
  }

#pragma unroll
  for (int nt = 0; nt < 8; ++nt) {
    float bb = b2[nt * 16 + l15];
#pragma unroll
    for (int r = 0; r < 4; ++r) {
      long e = e0 + lh * 4 + r;
      if (e < nE) out[e * 128 + nt * 16 + l15] = o[nt][r] + bb;
    }
  }
}

extern "C" void kernel_launch(void* const* d_in, const int* in_sizes, int n_in,
                              void* d_out, int out_size, void* d_ws,
                              size_t ws_size, hipStream_t stream) {
  const float* src = (const float*)d_in[0];
  const float* dst = (const float*)d_in[1];
  const float* ea = (const float*)d_in[2];
  // d_in[3] = u (unused), d_in[4] = batch (unused)
  const float* W1 = (const float*)d_in[5];
  const float* b1 = (const float*)d_in[6];
  const float* W2 = (const float*)d_in[7];
  const float* b2 = (const float*)d_in[8];
  float* out = (float*)d_out;

  const int nE = in_sizes[0] / 512;             // 200000
  const long strips = (nE + 15) / 16;           // 12500
  const int nblocks = (int)((strips + 3) / 4);  // 3125

  unsigned short* wsB1 = (unsigned short*)d_ws;
  unsigned short* wsB2 = wsB1 + 40960;
  const bool use_ws = ws_size >= 45056 * sizeof(unsigned short);

  if (use_ws) {
    prep_w_kernel<<<176, 256, 0, stream>>>(W1, W2, wsB1, wsB2);
    edge_mlp_kernel<true><<<nblocks, 256, 0, stream>>>(
        src, dst, ea, W1, b1, W2, b2, wsB1, wsB2, out, nE);
  } else {
    edge_mlp_kernel<false><<<nblocks, 256, 0, stream>>>(
        src, dst, ea, W1, b1, W2, b2, nullptr, nullptr, out, nE);
  }
}

// Round 4
// 247.404 us; speedup vs baseline: 1.0493x; 1.0493x over previous
//
#include <hip/hip_runtime.h>
#include <hip/hip_bf16.h>

typedef __bf16 bf16x8 __attribute__((ext_vector_type(8)));
typedef unsigned short u16x8 __attribute__((ext_vector_type(8)));
typedef float f32x4 __attribute__((ext_vector_type(4)));
typedef unsigned int u32x4 __attribute__((ext_vector_type(4)));

// ---------------------------------------------------------------------------
// Prep: pack W1 [1280x32] and W2 [32x128] (f32, row-major) into bf16 MFMA
// B-fragment order for mfma_f32_16x16x32_bf16.
// Fragment element (lane l, elem j) <- W[k = kt*32 + (l>>4)*8 + j][n = nt*16 + (l&15)]
// wsB1[((kt*2+nt)*64 + l)*8 + j], wsB2[((nt)*64 + l)*8 + j]
// ---------------------------------------------------------------------------
__global__ __launch_bounds__(256) void prep_w_kernel(
    const float* __restrict__ W1, const float* __restrict__ W2,
    unsigned short* __restrict__ wsB1, unsigned short* __restrict__ wsB2) {
  int tid = blockIdx.x * 256 + threadIdx.x;
  if (tid < 40960) {                      // W1 frags: 40 ktiles * 2 ntiles * 512
    int j = tid & 7, l = (tid >> 3) & 63, nt = (tid >> 9) & 1, kt = tid >> 10;
    int k = kt * 32 + ((l >> 4) << 3) + j;
    int n = nt * 16 + (l & 15);
    __bf16 v = (__bf16)W1[k * 32 + n];
    wsB1[tid] = __builtin_bit_cast(unsigned short, v);
  } else if (tid < 45056) {               // W2 frags: 8 ntiles * 512
    int t = tid - 40960;
    int j = t & 7, l = (t >> 3) & 63, nt = t >> 9;
    int k = ((l >> 4) << 3) + j;
    int n = nt * 16 + (l & 15);
    __bf16 v = (__bf16)W2[k * 128 + n];
    wsB2[t] = __builtin_bit_cast(unsigned short, v);
  }
}

__device__ __forceinline__ u32x4 make_srd(const void* p, unsigned bytes) {
  u32x4 r;
  r[0] = (unsigned)(unsigned long long)p;
  r[1] = (unsigned)(((unsigned long long)p) >> 32);
  r[2] = bytes;
  r[3] = 0x00020000u;
  return r;
}

// asm pipeline primitives -----------------------------------------------------
// XLD: load one x tile: per-lane 32B = two dwordx4 at OFF0 and OFF1 = OFF0+16.
// (R3 bug: OFF1 was OFF0+64 -> a[4..7] read another lane's data.)
#define XLD(SLOT, VOFF, OFF0, OFF1)                                        \
  asm volatile("buffer_load_dwordx4 %0, %2, %3, 0 offen offset:" #OFF0     \
               "\n\tbuffer_load_dwordx4 %1, %2, %3, 0 offen offset:" #OFF1 \
               : "=&v"(px[SLOT][0]), "=&v"(px[SLOT][1])                    \
               : "v"(VOFF), "s"(srdX))
// WLD: load one weight tile (2 frags x 16B per lane); tile byte offset via
// soffset SGPR; frag1 is +1024B.
#define WLD(SLOT, SOFF)                                                    \
  asm volatile("buffer_load_dwordx4 %0, %2, %3, %4 offen offset:0"         \
               "\n\tbuffer_load_dwordx4 %1, %2, %3, %4 offen offset:1024"  \
               : "=&v"(pw[SLOT][0]), "=&v"(pw[SLOT][1])                    \
               : "v"(voffw), "s"(srdw), "s"((unsigned)(SOFF)))
// VMW: counted wait + scheduling fence (rule #18: consumers must not hoist).
#define VMW(N)                                                \
  do {                                                        \
    asm volatile("s_waitcnt vmcnt(" #N ")" ::: "memory");     \
    __builtin_amdgcn_sched_barrier(0);                        \
  } while (0)
// CONS: convert x slot to bf16 fragment, 2 MFMAs against weight slot.
#define CONS(SX, SW)                                                          \
  do {                                                                        \
    f32x4 lo = px[SX][0], hi = px[SX][1];                                     \
    bf16x8 a;                                                                 \
    a[0] = (__bf16)lo[0]; a[1] = (__bf16)lo[1];                               \
    a[2] = (__bf16)lo[2]; a[3] = (__bf16)lo[3];                               \
    a[4] = (__bf16)hi[0]; a[5] = (__bf16)hi[1];                               \
    a[6] = (__bf16)hi[2]; a[7] = (__bf16)hi[3];                               \
    acc0 = __builtin_amdgcn_mfma_f32_16x16x32_bf16(                           \
        a, __builtin_bit_cast(bf16x8, pw[SW][0]), acc0, 0, 0, 0);             \
    acc1 = __builtin_amdgcn_mfma_f32_16x16x32_bf16(                           \
        a, __builtin_bit_cast(bf16x8, pw[SW][1]), acc1, 0, 0, 0);             \
  } while (0)

// ---------------------------------------------------------------------------
// Main: one wave per strip of 16 edges.
// GEMM1 k-loop: 40 tiles, inline-asm buffer_load pipeline (depth 6 x-stream,
// depth 4 w-stream, shared per-wave vmcnt queue, counted waits).
// Then per-wave LDS transpose of h, GEMM2: out[16][128] = h @ W2 + b2.
// ---------------------------------------------------------------------------
template <bool USE_WS>
__global__ __launch_bounds__(256, 4) void edge_mlp_kernel(
    const float* __restrict__ src, const float* __restrict__ dst,
    const float* __restrict__ ea, const float* __restrict__ W1,
    const float* __restrict__ b1, const float* __restrict__ W2,
    const float* __restrict__ b2, const unsigned short* __restrict__ wsB1,
    const unsigned short* __restrict__ wsB2, float* __restrict__ out, int nE) {
  __shared__ alignas(16) unsigned short hbuf_s[4][16 * 40];  // 40 = padded stride
  const int lane = threadIdx.x & 63;
  const int wave = threadIdx.x >> 6;
  const int l15 = lane & 15;
  const int lh = lane >> 4;
  const long strip = (long)blockIdx.x * 4 + wave;
  const long e0 = strip * 16;
  if (e0 >= nE) return;
  long row = e0 + l15;
  if (row >= nE) row = nE - 1;

  f32x4 acc0 = {0.f, 0.f, 0.f, 0.f};
  f32x4 acc1 = {0.f, 0.f, 0.f, 0.f};

  if constexpr (USE_WS) {
    // SRSRC descriptors (T8): bounds = exact buffer sizes.
    const u32x4 srdS = make_srd(src, (unsigned)nE * 2048u);
    const u32x4 srdD = make_srd(dst, (unsigned)nE * 2048u);
    const u32x4 srdE = make_srd(ea, (unsigned)nE * 1024u);
    const u32x4 srdw = make_srd(wsB1, 81920u);
    // per-lane voffsets: row-major f32 rows; lane covers cols [lh*8, lh*8+8)
    const unsigned voffx = (unsigned)row * 2048u + (unsigned)lh * 32u;
    const unsigned voffe = (unsigned)row * 1024u + (unsigned)lh * 32u;
    const unsigned voffw = (unsigned)lane * 16u;

    f32x4 px[6][2];
    u16x8 pw[4][2];

    // Prologue issue order: x0,w0,x1,w1,x2,w2,x3,w3,x4,x5  (20 loads)
    {
      const u32x4 srdX = srdS;
      XLD(0, voffx, 0, 16);       WLD(0, 0);
      XLD(1, voffx, 128, 144);    WLD(1, 2048);
      XLD(2, voffx, 256, 272);    WLD(2, 4096);
      XLD(3, voffx, 384, 400);    WLD(3, 6144);
      XLD(4, voffx, 512, 528);
      XLD(5, voffx, 640, 656);

      // Steady iterations: VMW(W) ; CONS(t%6, t%4) ; issue x(t+6), w(t+4)
      VMW(16); CONS(0, 0); XLD(0, voffx, 768, 784);    WLD(0, 8192);
      VMW(16); CONS(1, 1); XLD(1, voffx, 896, 912);    WLD(1, 10240);
      VMW(16); CONS(2, 2); XLD(2, voffx, 1024, 1040);  WLD(2, 12288);
      VMW(16); CONS(3, 3); XLD(3, voffx, 1152, 1168);  WLD(3, 14336);
      VMW(12); CONS(4, 0); XLD(4, voffx, 1280, 1296);  WLD(0, 16384);
      VMW(12); CONS(5, 1); XLD(5, voffx, 1408, 1424);  WLD(1, 18432);
      VMW(12); CONS(0, 2); XLD(0, voffx, 1536, 1552);  WLD(2, 20480);
      VMW(12); CONS(1, 3); XLD(1, voffx, 1664, 1680);  WLD(3, 22528);
      VMW(12); CONS(2, 0); XLD(2, voffx, 1792, 1808);  WLD(0, 24576);
      VMW(12); CONS(3, 1); XLD(3, voffx, 1920, 1936);  WLD(1, 26624);
    }
    {  // x-stream switches to dst
      const u32x4 srdX = srdD;
      VMW(12); CONS(4, 2); XLD(4, voffx, 0, 16);       WLD(2, 28672);
      VMW(12); CONS(5, 3); XLD(5, voffx, 128, 144);    WLD(3, 30720);
      VMW(12); CONS(0, 0); XLD(0, voffx, 256, 272);    WLD(0, 32768);
      VMW(12); CONS(1, 1); XLD(1, voffx, 384, 400);    WLD(1, 34816);
      VMW(12); CONS(2, 2); XLD(2, voffx, 512, 528);    WLD(2, 36864);
      VMW(12); CONS(3, 3); XLD(3, voffx, 640, 656);    WLD(3, 38912);
      VMW(12); CONS(4, 0); XLD(4, voffx, 768, 784);    WLD(0, 40960);
      VMW(12); CONS(5, 1); XLD(5, voffx, 896, 912);    WLD(1, 43008);
      VMW(12); CONS(0, 2); XLD(0, voffx, 1024, 1040);  WLD(2, 45056);
      VMW(12); CONS(1, 3); XLD(1, voffx, 1152, 1168);  WLD(3, 47104);
      VMW(12); CONS(2, 0); XLD(2, voffx, 1280, 1296);  WLD(0, 49152);
      VMW(12); CONS(3, 1); XLD(3, voffx, 1408, 1424);  WLD(1, 51200);
      VMW(12); CONS(4, 2); XLD(4, voffx, 1536, 1552);  WLD(2, 53248);
      VMW(12); CONS(5, 3); XLD(5, voffx, 1664, 1680);  WLD(3, 55296);
      VMW(12); CONS(0, 0); XLD(0, voffx, 1792, 1808);  WLD(0, 57344);
      VMW(12); CONS(1, 1); XLD(1, voffx, 1920, 1936);  WLD(1, 59392);
    }
    {  // x-stream switches to edge_attr
      const u32x4 srdX = srdE;
      VMW(12); CONS(2, 2); XLD(2, voffe, 0, 16);       WLD(2, 61440);
      VMW(12); CONS(3, 3); XLD(3, voffe, 128, 144);    WLD(3, 63488);
      VMW(12); CONS(4, 0); XLD(4, voffe, 256, 272);    WLD(0, 65536);
      VMW(12); CONS(5, 1); XLD(5, voffe, 384, 400);    WLD(1, 67584);
      VMW(12); CONS(0, 2); XLD(0, voffe, 512, 528);    WLD(2, 69632);
      VMW(12); CONS(1, 3); XLD(1, voffe, 640, 656);    WLD(3, 71680);
      VMW(12); CONS(2, 0); XLD(2, voffe, 768, 784);    WLD(0, 73728);
      VMW(12); CONS(3, 1); XLD(3, voffe, 896, 912);    WLD(1, 75776);
      VMW(12); CONS(4, 2);                             WLD(2, 77824);
      VMW(10); CONS(5, 3);                             WLD(3, 79872);
      VMW(8);  CONS(0, 0);
      VMW(4);  CONS(1, 1);
      VMW(2);  CONS(2, 2);
      VMW(0);  CONS(3, 3);
    }
  } else {
    // correctness fallback (no workspace): plain serial loop
    for (int t = 0; t < 40; ++t) {
      const float* p = (t < 16) ? (src + row * 512 + t * 32 + lh * 8)
                     : (t < 32) ? (dst + row * 512 + (t - 16) * 32 + lh * 8)
                                : (ea + row * 256 + (t - 32) * 32 + lh * 8);
      f32x4 lo = *(const f32x4*)p;
      f32x4 hi = *(const f32x4*)(p + 4);
      bf16x8 a, bf0, bf1;
      a[0] = (__bf16)lo[0]; a[1] = (__bf16)lo[1];
      a[2] = (__bf16)lo[2]; a[3] = (__bf16)lo[3];
      a[4] = (__bf16)hi[0]; a[5] = (__bf16)hi[1];
      a[6] = (__bf16)hi[2]; a[7] = (__bf16)hi[3];
#pragma unroll
      for (int j = 0; j < 8; ++j) {
        int k = t * 32 + lh * 8 + j;
        bf0[j] = (__bf16)W1[k * 32 + l15];
        bf1[j] = (__bf16)W1[k * 32 + 16 + l15];
      }
      acc0 = __builtin_amdgcn_mfma_f32_16x16x32_bf16(a, bf0, acc0, 0, 0, 0);
      acc1 = __builtin_amdgcn_mfma_f32_16x16x32_bf16(a, bf1, acc1, 0, 0, 0);
    }
  }

  // ---- bias + ELU, write h (bf16) to LDS in C-layout positions ----
  const float bias0 = b1[l15];
  const float bias1 = b1[16 + l15];
  unsigned short* hl = hbuf_s[wave];
#pragma unroll
  for (int r = 0; r < 4; ++r) {
    int hrow = lh * 4 + r;  // C/D layout: row=(lane>>4)*4+reg, col=lane&15
    float h0 = acc0[r] + bias0;
    float h1 = acc1[r] + bias1;
    h0 = h0 > 0.f ? h0 : (__expf(h0) - 1.f);
    h1 = h1 > 0.f ? h1 : (__expf(h1) - 1.f);
    __bf16 v0 = (__bf16)h0, v1 = (__bf16)h1;
    hl[hrow * 40 + l15] = __builtin_bit_cast(unsigned short, v0);
    hl[hrow * 40 + 16 + l15] = __builtin_bit_cast(unsigned short, v1);
  }
  // wave-local transpose: drain ds_writes, fence, read A-fragment layout
  asm volatile("s_waitcnt lgkmcnt(0)" ::: "memory");
  __builtin_amdgcn_sched_barrier(0);
  bf16x8 ha =
      __builtin_bit_cast(bf16x8, *(const u16x8*)(hl + l15 * 40 + lh * 8));

  // ---- GEMM2: out tiles over 8 ntiles of 16 cols ----
  f32x4 o[8];
#pragma unroll
  for (int nt = 0; nt < 8; ++nt) {
    bf16x8 bw;
    if (USE_WS) {
      bw = __builtin_bit_cast(bf16x8, *(const u16x8*)(wsB2 + nt * 512 + lane * 8));
    } else {
#pragma unroll
      for (int j = 0; j < 8; ++j)
        bw[j] = (__bf16)W2[(lh * 8 + j) * 128 + nt * 16 + l15];
    }
    f32x4 z = {0.f, 0.f, 0.f, 0.f};
    o[nt] = __builtin_amdgcn_mfma_f32_16x16x32_bf16(ha, bw, z, 0, 0, 0);
  }

#pragma unroll
  for (int nt = 0; nt < 8; ++nt) {
    float bb = b2[nt * 16 + l15];
#pragma unroll
    for (int r = 0; r < 4; ++r) {
      long e = e0 + lh * 4 + r;
      if (e < nE) out[e * 128 + nt * 16 + l15] = o[nt][r] + bb;
    }
  }
}

extern "C" void kernel_launch(void* const* d_in, const int* in_sizes, int n_in,
                              void* d_out, int out_size, void* d_ws,
                              size_t ws_size, hipStream_t stream) {
  const float* src = (const float*)d_in[0];
  const float* dst = (const float*)d_in[1];
  const float* ea = (const float*)d_in[2];
  // d_in[3] = u (unused), d_in[4] = batch (unused)
  const float* W1 = (const float*)d_in[5];
  const float* b1 = (const float*)d_in[6];
  const float* W2 = (const float*)d_in[7];
  const float* b2 = (const float*)d_in[8];
  float* out = (float*)d_out;

  const int nE = in_sizes[0] / 512;             // 200000
  const long strips = (nE + 15) / 16;           // 12500
  const int nblocks = (int)((strips + 3) / 4);  // 3125

  unsigned short* wsB1 = (unsigned short*)d_ws;
  unsigned short* wsB2 = wsB1 + 40960;
  const bool use_ws = ws_size >= 45056 * sizeof(unsigned short);

  if (use_ws) {
    prep_w_kernel<<<176, 256, 0, stream>>>(W1, W2, wsB1, wsB2);
    edge_mlp_kernel<true><<<nblocks, 256, 0, stream>>>(
        src, dst, ea, W1, b1, W2, b2, wsB1, wsB2, out, nE);
  } else {
    edge_mlp_kernel<false><<<nblocks, 256, 0, stream>>>(
        src, dst, ea, W1, b1, W2, b2, nullptr, nullptr, out, nE);
  }
}